// Round 10
// baseline (386.248 us; speedup 1.0000x reference)
//
#include <hip/hip_runtime.h>

#define BM 128
#define BN 128
#define BKH 32   // K-half; one barrier pair covers 2 halves (BK=64)

typedef __bf16 bf16x8 __attribute__((ext_vector_type(8)));
typedef __bf16 bf16x4 __attribute__((ext_vector_type(4)));
typedef float f32x4 __attribute__((ext_vector_type(4)));
typedef __bf16 bf16_t;

__device__ __forceinline__ void gl_lds16(const void* g, void* l) {
    __builtin_amdgcn_global_load_lds(
        (const __attribute__((address_space(1))) void*)g,
        (__attribute__((address_space(3))) void*)l, 16, 0, 0);
}

// fp32 -> bf16 conversion for hid + 4 weight matrices in ONE launch.
__global__ __launch_bounds__(256)
void cvt_all_kernel(const float* __restrict__ hid,
                    const float* __restrict__ w0, const float* __restrict__ w1,
                    const float* __restrict__ w2, const float* __restrict__ w3,
                    bf16_t* __restrict__ hidb, bf16_t* __restrict__ wb)
{
    const int bid = blockIdx.x;
    const float* src;
    bf16_t* dst;
    size_t off;
    if (bid < 8192) {
        src = hid; dst = hidb; off = (size_t)bid * 1024;
    } else {
        const int i = (bid - 8192) >> 10;
        src = (i == 0) ? w0 : (i == 1) ? w1 : (i == 2) ? w2 : w3;
        dst = wb + (size_t)i * 1024 * 1024;
        off = (size_t)((bid - 8192) & 1023) * 1024;
    }
    const size_t idx = off + threadIdx.x * 4;
    const float4 v = *(const float4*)(src + idx);
    bf16x4 o;
    o[0] = (__bf16)v.x; o[1] = (__bf16)v.y;
    o[2] = (__bf16)v.z; o[3] = (__bf16)v.w;
    *(bf16x4*)(dst + idx) = o;
}

// Generic NT GEMM: C[m,n] = sum_k A[m,k] * Bw[n,k]  (+ epilogue per MODE)
// MODE 0: QKV fused over z: z=0 -> Wq/bq; z=1 -> Wk/bk; z=2 -> Wv/bv transposed
//         (B = 2 MB/layer fits per-XCD L2 — measured best; N=3072 merge thrashes)
// MODE 3: plain bf16 store, batched z                  [scores, PV]
// MODE 4: + bias[n] + resid[m,n] (bf16), bf16 out      [out-proj + residual]
// SWIZ=1: 1D x-grid, grouped decode (GM=8): same-XCD blocks share one A-tile.
// SWIZ=0: plain 2D (blockIdx.x = n-tile, blockIdx.y = m-tile).
template <int MODE, int SWIZ>
__global__ __launch_bounds__(256)
void gemm_bt(const bf16_t* __restrict__ A, const bf16_t* __restrict__ Bw,
             const float* __restrict__ bias, const float* __restrict__ bias2,
             const float* __restrict__ bias3,
             bf16_t* __restrict__ C, bf16_t* __restrict__ C2,
             int M, int N, int K,
             long long sAz, long long sBz, long long sCz,
             const bf16_t* __restrict__ resid,
             int Sdim, int DHdim)
{
    const int bz = blockIdx.z;
    const float* bi = bias;
    if (MODE == 0) {
        Bw += (long long)bz * N * K;        // Wq | Wk | Wv contiguous
        bi = (bz == 0) ? bias : (bz == 1 ? bias2 : bias3);
        if (bz < 2) C += (long long)bz * sCz;
    } else {
        A += (long long)bz * sAz;
        Bw += (long long)bz * sBz;
        C += (long long)bz * sCz;
    }

    int m0, n0;
    if (SWIZ) {
        const int num_n = N / BN;
        const int pid = blockIdx.x;
        const int group = 8 * num_n;         // 8 m-tiles per group
        const int g = pid / group;
        m0 = (g * 8 + (pid % 8)) * BM;
        n0 = ((pid % group) / 8) * BN;
    } else {
        m0 = blockIdx.y * BM;
        n0 = blockIdx.x * BN;
    }
    const int tid = threadIdx.x;
    const int w = tid >> 6;          // wave id 0..3
    const int lane = tid & 63;
    const int wr = w >> 1;           // wave row (2x2 wave grid, 64x64 each)
    const int wc = w & 1;
    const int srow = lane >> 2;      // staging: row within 16-row slice
    const int scol = (lane & 3) * 8; // staging: bf16 col offset (16B chunks)
    const int frow = lane & 15;      // fragment m/n index
    const int fk = (lane >> 4) * 8;  // fragment k base

    __shared__ bf16_t smem[4 * BM * BKH];   // 32 KB: A0 | A1 | B0 | B1
    bf16_t* A0 = smem;
    bf16_t* A1 = smem + BM * BKH;
    bf16_t* B0 = smem + 2 * BM * BKH;
    bf16_t* B1 = smem + 3 * BM * BKH;

    f32x4 acc[4][4];
#pragma unroll
    for (int i = 0; i < 4; ++i)
#pragma unroll
        for (int j = 0; j < 4; ++j) acc[i][j] = (f32x4)0.0f;

    for (int k0 = 0; k0 < K; k0 += 2 * BKH) {
#pragma unroll
        for (int i = 0; i < 2; ++i) {
            const int r = i * 64 + w * 16;
            const bf16_t* ga = A + (size_t)(m0 + r + srow) * K + (k0 + scol);
            const bf16_t* gb = Bw + (size_t)(n0 + r + srow) * K + (k0 + scol);
            gl_lds16(ga,        &A0[r * BKH]);
            gl_lds16(ga + BKH,  &A1[r * BKH]);
            gl_lds16(gb,        &B0[r * BKH]);
            gl_lds16(gb + BKH,  &B1[r * BKH]);
        }
        __syncthreads();
#pragma unroll
        for (int h = 0; h < 2; ++h) {
            const bf16_t* Ah = h ? A1 : A0;
            const bf16_t* Bh = h ? B1 : B0;
            bf16x8 af[4], bfv[4];
#pragma unroll
            for (int t = 0; t < 4; ++t) {
                af[t]  = *(const bf16x8*)&Ah[(wr * 64 + t * 16 + frow) * BKH + fk];
                bfv[t] = *(const bf16x8*)&Bh[(wc * 64 + t * 16 + frow) * BKH + fk];
            }
#pragma unroll
            for (int mt = 0; mt < 4; ++mt)
#pragma unroll
                for (int nt = 0; nt < 4; ++nt)
                    acc[mt][nt] = __builtin_amdgcn_mfma_f32_16x16x32_bf16(
                        af[mt], bfv[nt], acc[mt][nt], 0, 0, 0);
        }
        __syncthreads();
    }
    // After the final __syncthreads all LDS reads are drained; smem reusable.

    // C/D layout: col = lane&15, row = (lane>>4)*4 + reg
    const int crow = (lane >> 4) * 4;
    const int ccol = lane & 15;

    if (MODE == 0 && bz == 2) {
        // V projection: transposed store vT[b][n][s]
#pragma unroll
        for (int mt = 0; mt < 4; ++mt) {
            const int mb = m0 + wr * 64 + mt * 16 + crow;
#pragma unroll
            for (int nt = 0; nt < 4; ++nt) {
                const int n = n0 + wc * 64 + nt * 16 + ccol;
                const float bv = bi[n];
                const int b = mb >> 11;      // S = 2048 tokens per batch
                const int s = mb & 2047;
                union { ushort4 u; bf16_t h[4]; } pk;
#pragma unroll
                for (int r = 0; r < 4; ++r) pk.h[r] = (__bf16)(acc[mt][nt][r] + bv);
                *(ushort4*)&C2[(size_t)b * DHdim * Sdim + (size_t)n * Sdim + s] = pk.u;
            }
        }
        return;
    }

    // ---- transpose epilogue ----
    bf16_t* tw = smem + w * (16 * 72);
    const int r0 = lane >> 3;            // 0..7 : row within 16-slice
    const int cseg = (lane & 7) * 8;     // 8-col segment base

    float bv[4];
    if (MODE == 0 || MODE == 4) {
#pragma unroll
        for (int nt = 0; nt < 4; ++nt)
            bv[nt] = bi[n0 + wc * 64 + nt * 16 + ccol];
    }

#pragma unroll
    for (int mt = 0; mt < 4; ++mt) {
#pragma unroll
        for (int nt = 0; nt < 4; ++nt) {
            const float badd = (MODE == 0 || MODE == 4) ? bv[nt] : 0.0f;
#pragma unroll
            for (int r = 0; r < 4; ++r)
                tw[(crow + r) * 72 + nt * 16 + ccol] = (__bf16)(acc[mt][nt][r] + badd);
        }
        bf16x8 va = *(const bf16x8*)&tw[r0 * 72 + cseg];
        bf16x8 vb = *(const bf16x8*)&tw[(r0 + 8) * 72 + cseg];

        const int gm_a = m0 + wr * 64 + mt * 16 + r0;
        const int gm_b = gm_a + 8;
        const int gn = n0 + wc * 64 + cseg;

        if (MODE == 0 || MODE == 3) {
            *(bf16x8*)&C[(size_t)gm_a * N + gn] = va;
            *(bf16x8*)&C[(size_t)gm_b * N + gn] = vb;
        } else {  // MODE 4: + residual (bf16), bf16 out
            const bf16x8 xa = *(const bf16x8*)&resid[(size_t)gm_a * N + gn];
            const bf16x8 xb = *(const bf16x8*)&resid[(size_t)gm_b * N + gn];
            bf16x8 oa, ob;
#pragma unroll
            for (int j = 0; j < 8; ++j) {
                oa[j] = (__bf16)((float)va[j] + (float)xa[j]);
                ob[j] = (__bf16)((float)vb[j] + (float)xb[j]);
            }
            *(bf16x8*)&C[(size_t)gm_a * N + gn] = oa;
            *(bf16x8*)&C[(size_t)gm_b * N + gn] = ob;
        }
    }
}

// Fused softmax over S=2048, ONE row per 256-thread block (R7-measured best):
// d1 = q[row]·de[1] in-block; v = s/32 + mask + (rel==1 ? d1/32 : 0);
// max/exp/sum; write probs bf16.
__global__ __launch_bounds__(256)
void softmax_kernel(bf16_t* __restrict__ sc, const int* __restrict__ rel,
                    const bf16_t* __restrict__ q, const float* __restrict__ de,
                    const float* __restrict__ mask)
{
    constexpr int S = 2048, H = 1024;
    const int row = blockIdx.x;
    const int b = row >> 11;             // 2048 rows per batch
    const int tid = threadIdx.x;
    const int w = tid >> 6, lane = tid & 63;
    __shared__ float rd1[4], rmax[4], rsum[4];

    // ---- d1 = q[row,:] . de[1,:] ----
    const bf16x4 q4 = *(const bf16x4*)(q + (size_t)row * H + tid * 4);
    const float4 e4 = *(const float4*)(de + H + tid * 4);
    float pd = (float)q4[0] * e4.x + (float)q4[1] * e4.y
             + (float)q4[2] * e4.z + (float)q4[3] * e4.w;
#pragma unroll
    for (int off = 32; off; off >>= 1) pd += __shfl_xor(pd, off, 64);
    if (lane == 0) rd1[w] = pd;
    __syncthreads();
    const float d1s = (rd1[0] + rd1[1] + rd1[2] + rd1[3]) * 0.03125f;

    bf16_t* p = sc + (size_t)row * S;
    const bf16x8 x = *(const bf16x8*)(p + tid * 8);
    const int4 rl0 = *(const int4*)&rel[(size_t)row * S + tid * 8];
    const int4 rl1 = *(const int4*)&rel[(size_t)row * S + tid * 8 + 4];
    const float4 mk0 = *(const float4*)&mask[(size_t)b * S + tid * 8];
    const float4 mk1 = *(const float4*)&mask[(size_t)b * S + tid * 8 + 4];
    const int rls[8] = {rl0.x, rl0.y, rl0.z, rl0.w, rl1.x, rl1.y, rl1.z, rl1.w};
    const float mks[8] = {mk0.x, mk0.y, mk0.z, mk0.w, mk1.x, mk1.y, mk1.z, mk1.w};
    float v[8];
    float mx = -1e30f;
#pragma unroll
    for (int j = 0; j < 8; ++j) {
        v[j] = (float)x[j] * 0.03125f + mks[j] + (rls[j] == 1 ? d1s : 0.0f);
        mx = fmaxf(mx, v[j]);
    }
#pragma unroll
    for (int off = 32; off; off >>= 1) mx = fmaxf(mx, __shfl_xor(mx, off, 64));
    if (lane == 0) rmax[w] = mx;
    __syncthreads();
    mx = fmaxf(fmaxf(rmax[0], rmax[1]), fmaxf(rmax[2], rmax[3]));
    float sum = 0.0f;
#pragma unroll
    for (int j = 0; j < 8; ++j) { v[j] = __expf(v[j] - mx); sum += v[j]; }
#pragma unroll
    for (int off = 32; off; off >>= 1) sum += __shfl_xor(sum, off, 64);
    if (lane == 0) rsum[w] = sum;
    __syncthreads();
    sum = rsum[0] + rsum[1] + rsum[2] + rsum[3];
    const float inv = 1.0f / sum;
    bf16x8 o;
#pragma unroll
    for (int j = 0; j < 8; ++j) o[j] = (__bf16)(v[j] * inv);
    *(bf16x8*)(p + tid * 8) = o;
}

// LayerNorm over H=1024, bf16 in / fp32 out. 2 rows per 256-thr block.
__global__ __launch_bounds__(256)
void ln_kernel(const bf16_t* __restrict__ x, const float* __restrict__ gamma,
               const float* __restrict__ beta, float* __restrict__ out)
{
    const int H = 1024;
    const int tid = threadIdx.x;
    const int half = tid >> 7;
    const int t7 = tid & 127;
    const size_t row = (size_t)blockIdx.x * 2 + half;
    const int w = tid >> 6, lane = tid & 63;
    const bf16x8 xv = *(const bf16x8*)(x + row * H + t7 * 8);
    float v[8], s = 0.0f, s2 = 0.0f;
#pragma unroll
    for (int j = 0; j < 8; ++j) {
        v[j] = (float)xv[j];
        s += v[j]; s2 += v[j] * v[j];
    }
#pragma unroll
    for (int off = 32; off; off >>= 1) {
        s += __shfl_xor(s, off, 64);
        s2 += __shfl_xor(s2, off, 64);
    }
    __shared__ float rs[4], rs2[4];
    if (lane == 0) { rs[w] = s; rs2[w] = s2; }
    __syncthreads();
    s  = rs[half * 2] + rs[half * 2 + 1];
    s2 = rs2[half * 2] + rs2[half * 2 + 1];
    const float mu  = s * (1.0f / H);
    const float var = s2 * (1.0f / H) - mu * mu;
    const float inv = rsqrtf(var + 1e-12f);
    const int c = t7 * 8;
    float4 o0, o1;
    o0.x = (v[0] - mu) * inv * gamma[c + 0] + beta[c + 0];
    o0.y = (v[1] - mu) * inv * gamma[c + 1] + beta[c + 1];
    o0.z = (v[2] - mu) * inv * gamma[c + 2] + beta[c + 2];
    o0.w = (v[3] - mu) * inv * gamma[c + 3] + beta[c + 3];
    o1.x = (v[4] - mu) * inv * gamma[c + 4] + beta[c + 4];
    o1.y = (v[5] - mu) * inv * gamma[c + 5] + beta[c + 5];
    o1.z = (v[6] - mu) * inv * gamma[c + 6] + beta[c + 6];
    o1.w = (v[7] - mu) * inv * gamma[c + 7] + beta[c + 7];
    *(float4*)(out + row * H + c) = o0;
    *(float4*)(out + row * H + c + 4) = o1;
}

extern "C" void kernel_launch(void* const* d_in, const int* in_sizes, int n_in,
                              void* d_out, int out_size, void* d_ws, size_t ws_size,
                              hipStream_t stream)
{
    constexpr int B = 4, S = 2048, H = 1024;
    const float* hid = (const float*)d_in[0];
    const float* am  = (const float*)d_in[1];
    const int*   rel = (const int*)d_in[2];
    const float* Wq  = (const float*)d_in[3];
    const float* bq  = (const float*)d_in[4];
    const float* Wk  = (const float*)d_in[5];
    const float* bk  = (const float*)d_in[6];
    const float* Wv  = (const float*)d_in[7];
    const float* bv  = (const float*)d_in[8];
    const float* de  = (const float*)d_in[9];
    const float* Wo  = (const float*)d_in[10];
    const float* bo  = (const float*)d_in[11];
    const float* lng = (const float*)d_in[12];
    const float* lnb = (const float*)d_in[13];
    float* out = (float*)d_out;

    char* ws = (char*)d_ws;
    const int n_tok = B * S;                               // 8192
    const size_t MB = 1024 * 1024;
    bf16_t* hidb = (bf16_t*)(ws);                          // 16 MB
    bf16_t* Wqb  = (bf16_t*)(ws + 16 * MB);                // 2 MB each; Wq/Wk/Wv/Wo contiguous
    bf16_t* Wob  = (bf16_t*)(ws + 22 * MB);
    bf16_t* qb   = (bf16_t*)(ws + 24 * MB);                // 16 MB
    bf16_t* kb   = (bf16_t*)(ws + 40 * MB);                // 16 MB
    bf16_t* vT   = (bf16_t*)(ws + 56 * MB);                // 16 MB (B, DH, S)
    bf16_t* ctx  = (bf16_t*)(ws + 72 * MB);                // 16 MB
    bf16_t* sc   = (bf16_t*)(ws + 88 * MB);                // 32 MB (B,S,S)
    bf16_t* xb   = (bf16_t*)(ws + 88 * MB);                // 16 MB, ALIASES sc (sc dead after PV)

    const dim3 blk(256);
    // hid + Wq/Wk/Wv/Wo fp32->bf16 in one launch (weights contiguous at Wqb)
    cvt_all_kernel<<<dim3(8192 + 4 * 1024), blk, 0, stream>>>(
        hid, Wq, Wk, Wv, Wo, hidb, Wqb);

    // Q + K + V projections fused over z (B = 2 MB/layer fits per-XCD L2),
    // GM=8 swizzle: 64 m-tiles x 8 n-tiles per z-layer.
    gemm_bt<0, 1><<<dim3(64 * 8, 1, 3), blk, 0, stream>>>(
        hidb, Wqb, bq, bk, bv, qb, vT, n_tok, H, H,
        0, 0, (long long)n_tok * H,
        nullptr, S, H);
    // scores = q@k^T  (GM-swizzle — R7-measured best; rel/d1/scale/mask in softmax)
    gemm_bt<3, 1><<<dim3(16 * 16, 1, B), blk, 0, stream>>>(
        qb, kb, nullptr, nullptr, nullptr, sc, nullptr, S, S, H,
        (long long)S * H, (long long)S * H, (long long)S * S,
        nullptr, S, H);
    softmax_kernel<<<dim3(B * S), blk, 0, stream>>>(sc, rel, qb, de, am);
    // ctx = probs @ v  (2D grid — measured best)
    gemm_bt<3, 0><<<dim3(H / BN, S / BM, B), blk, 0, stream>>>(
        sc, vT, nullptr, nullptr, nullptr, ctx, nullptr, S, H, S,
        (long long)S * S, (long long)H * S, (long long)S * H,
        nullptr, S, H);
    // attn_out = ctx @ Wo^T + bo; x = attn_out + hidden(bf16)  (aliases sc)
    gemm_bt<4, 0><<<dim3(H / BN, n_tok / BM, 1), blk, 0, stream>>>(
        ctx, Wob, bo, nullptr, nullptr, xb, nullptr, n_tok, H, H, 0, 0, 0,
        hidb, S, H);
    ln_kernel<<<dim3(n_tok / 2), blk, 0, stream>>>(xb, lng, lnb, out);
}

// Round 11
// 381.526 us; speedup vs baseline: 1.0124x; 1.0124x over previous
//
#include <hip/hip_runtime.h>

#define BM 128
#define BN 128
#define BKH 32   // K-half; one barrier pair covers 2 halves (BK=64)

typedef __bf16 bf16x8 __attribute__((ext_vector_type(8)));
typedef __bf16 bf16x4 __attribute__((ext_vector_type(4)));
typedef float f32x4 __attribute__((ext_vector_type(4)));
typedef __bf16 bf16_t;

__device__ __forceinline__ void gl_lds16(const void* g, void* l) {
    __builtin_amdgcn_global_load_lds(
        (const __attribute__((address_space(1))) void*)g,
        (__attribute__((address_space(3))) void*)l, 16, 0, 0);
}

// fp32 -> bf16 conversion for hid + 4 weight matrices, plus rowsum zeroing,
// in ONE launch.
// blocks [0, 8192)      : hid (8192*1024 elems)
// blocks [8192, 12288)  : W[i] (1024*1024 elems each)
// blocks [12288, 12296) : zero rowsum (8192 floats)
__global__ __launch_bounds__(256)
void cvt_all_kernel(const float* __restrict__ hid,
                    const float* __restrict__ w0, const float* __restrict__ w1,
                    const float* __restrict__ w2, const float* __restrict__ w3,
                    bf16_t* __restrict__ hidb, bf16_t* __restrict__ wb,
                    float* __restrict__ rowsum)
{
    const int bid = blockIdx.x;
    if (bid >= 12288) {
        const int i = (bid - 12288) * 1024 + threadIdx.x * 4;
        *(float4*)(rowsum + i) = make_float4(0.f, 0.f, 0.f, 0.f);
        return;
    }
    const float* src;
    bf16_t* dst;
    size_t off;
    if (bid < 8192) {
        src = hid; dst = hidb; off = (size_t)bid * 1024;
    } else {
        const int i = (bid - 8192) >> 10;
        src = (i == 0) ? w0 : (i == 1) ? w1 : (i == 2) ? w2 : w3;
        dst = wb + (size_t)i * 1024 * 1024;
        off = (size_t)((bid - 8192) & 1023) * 1024;
    }
    const size_t idx = off + threadIdx.x * 4;
    const float4 v = *(const float4*)(src + idx);
    bf16x4 o;
    o[0] = (__bf16)v.x; o[1] = (__bf16)v.y;
    o[2] = (__bf16)v.z; o[3] = (__bf16)v.w;
    *(bf16x4*)(dst + idx) = o;
}

// Generic NT GEMM: C[m,n] = sum_k A[m,k] * Bw[n,k]  (+ epilogue per MODE)
// MODE 0: QKV fused over z: z=0 Wq/bq; z=1 Wk/bk; z=2 Wv/bv -> vT transposed
// MODE 4: + bias[n] + resid[m,n] (bf16), bf16 out      [out-proj + residual]
// MODE 5: scores+exp: in-loop d1 from A-fragments; epilogue computes
//         e = exp((acc + (rel==1)?d1)/32 + mask), atomicAdds row sums,
//         stores unnormalized e (softmax kernel eliminated).
// MODE 6: PV with deferred normalization: epilogue multiplies by 1/rowsum.
// SWIZ=1: 1D x-grid, grouped decode (GM=8). SWIZ=0: plain 2D.
template <int MODE, int SWIZ>
__global__ __launch_bounds__(256)
void gemm_bt(const bf16_t* __restrict__ A, const bf16_t* __restrict__ Bw,
             const float* __restrict__ bias, const float* __restrict__ bias2,
             const float* __restrict__ bias3,
             bf16_t* __restrict__ C, bf16_t* __restrict__ C2,
             int M, int N, int K,
             long long sAz, long long sBz, long long sCz,
             const bf16_t* __restrict__ resid,
             const int* __restrict__ rel, const float* __restrict__ maskp,
             const float* __restrict__ de1, float* __restrict__ rowsum,
             int Sdim, int DHdim)
{
    const int bz = blockIdx.z;
    const float* bi = bias;
    if (MODE == 0) {
        Bw += (long long)bz * N * K;        // Wq | Wk | Wv contiguous
        bi = (bz == 0) ? bias : (bz == 1 ? bias2 : bias3);
        if (bz < 2) C += (long long)bz * sCz;
    } else {
        A += (long long)bz * sAz;
        Bw += (long long)bz * sBz;
        C += (long long)bz * sCz;
    }

    int m0, n0;
    if (SWIZ) {
        const int num_n = N / BN;
        const int pid = blockIdx.x;
        const int group = 8 * num_n;         // 8 m-tiles per group
        const int g = pid / group;
        m0 = (g * 8 + (pid % 8)) * BM;
        n0 = ((pid % group) / 8) * BN;
    } else {
        m0 = blockIdx.y * BM;
        n0 = blockIdx.x * BN;
    }
    const int tid = threadIdx.x;
    const int w = tid >> 6;          // wave id 0..3
    const int lane = tid & 63;
    const int wr = w >> 1;           // wave row (2x2 wave grid, 64x64 each)
    const int wc = w & 1;
    const int srow = lane >> 2;      // staging: row within 16-row slice
    const int scol = (lane & 3) * 8; // staging: bf16 col offset (16B chunks)
    const int frow = lane & 15;      // fragment m/n index
    const int fk = (lane >> 4) * 8;  // fragment k base

    __shared__ bf16_t smem[4 * BM * BKH];   // 32 KB: A0 | A1 | B0 | B1
    bf16_t* A0 = smem;
    bf16_t* A1 = smem + BM * BKH;
    bf16_t* B0 = smem + 2 * BM * BKH;
    bf16_t* B1 = smem + 3 * BM * BKH;
    // d1 scratch for MODE 5: aliases B0 region (dead after mainloop), 512 B
    float* d1f = (float*)(smem + 2 * BM * BKH);

    f32x4 acc[4][4];
#pragma unroll
    for (int i = 0; i < 4; ++i)
#pragma unroll
        for (int j = 0; j < 4; ++j) acc[i][j] = (f32x4)0.0f;

    float d1acc[4] = {0.f, 0.f, 0.f, 0.f};

    for (int k0 = 0; k0 < K; k0 += 2 * BKH) {
#pragma unroll
        for (int i = 0; i < 2; ++i) {
            const int r = i * 64 + w * 16;
            const bf16_t* ga = A + (size_t)(m0 + r + srow) * K + (k0 + scol);
            const bf16_t* gb = Bw + (size_t)(n0 + r + srow) * K + (k0 + scol);
            gl_lds16(ga,        &A0[r * BKH]);
            gl_lds16(ga + BKH,  &A1[r * BKH]);
            gl_lds16(gb,        &B0[r * BKH]);
            gl_lds16(gb + BKH,  &B1[r * BKH]);
        }
        __syncthreads();
#pragma unroll
        for (int h = 0; h < 2; ++h) {
            const bf16_t* Ah = h ? A1 : A0;
            const bf16_t* Bh = h ? B1 : B0;
            bf16x8 af[4], bfv[4];
#pragma unroll
            for (int t = 0; t < 4; ++t) {
                af[t]  = *(const bf16x8*)&Ah[(wr * 64 + t * 16 + frow) * BKH + fk];
                bfv[t] = *(const bf16x8*)&Bh[(wc * 64 + t * 16 + frow) * BKH + fk];
            }
            if (MODE == 5 && wc == 0) {
                // d1 partial from already-loaded A fragments (rows wr*64+t*16+frow)
                const float* dp = de1 + k0 + h * BKH + fk;
                const float4 e0 = *(const float4*)dp;
                const float4 e1 = *(const float4*)(dp + 4);
#pragma unroll
                for (int t = 0; t < 4; ++t) {
                    d1acc[t] += (float)af[t][0] * e0.x + (float)af[t][1] * e0.y
                              + (float)af[t][2] * e0.z + (float)af[t][3] * e0.w
                              + (float)af[t][4] * e1.x + (float)af[t][5] * e1.y
                              + (float)af[t][6] * e1.z + (float)af[t][7] * e1.w;
                }
            }
#pragma unroll
            for (int mt = 0; mt < 4; ++mt)
#pragma unroll
                for (int nt = 0; nt < 4; ++nt)
                    acc[mt][nt] = __builtin_amdgcn_mfma_f32_16x16x32_bf16(
                        af[mt], bfv[nt], acc[mt][nt], 0, 0, 0);
        }
        __syncthreads();
    }
    // After the final __syncthreads all LDS reads are drained; smem reusable.

    if (MODE == 5) {
        // finish d1: reduce over fk-groups (lanes ^16, ^32 share frow)
        if (wc == 0) {
#pragma unroll
            for (int t = 0; t < 4; ++t) {
                float s = d1acc[t];
                s += __shfl_xor(s, 16, 64);
                s += __shfl_xor(s, 32, 64);
                if (lane < 16) d1f[wr * 64 + t * 16 + lane] = s;
            }
        }
        __syncthreads();
    }

    // C/D layout: col = lane&15, row = (lane>>4)*4 + reg
    const int crow = (lane >> 4) * 4;
    const int ccol = lane & 15;

    if (MODE == 0 && bz == 2) {
        // V projection: transposed store vT[b][n][s]
#pragma unroll
        for (int mt = 0; mt < 4; ++mt) {
            const int mb = m0 + wr * 64 + mt * 16 + crow;
#pragma unroll
            for (int nt = 0; nt < 4; ++nt) {
                const int n = n0 + wc * 64 + nt * 16 + ccol;
                const float bv = bi[n];
                const int b = mb >> 11;      // S = 2048 tokens per batch
                const int s = mb & 2047;
                union { ushort4 u; bf16_t h[4]; } pk;
#pragma unroll
                for (int r = 0; r < 4; ++r) pk.h[r] = (__bf16)(acc[mt][nt][r] + bv);
                *(ushort4*)&C2[(size_t)b * DHdim * Sdim + (size_t)n * Sdim + s] = pk.u;
            }
        }
        return;
    }

    // ---- transpose epilogue ----
    bf16_t* tw = smem + w * (16 * 72);
    const int r0 = lane >> 3;            // 0..7 : row within 16-slice
    const int cseg = (lane & 7) * 8;     // 8-col segment base

    float bv[4];
    if (MODE == 0 || MODE == 4) {
#pragma unroll
        for (int nt = 0; nt < 4; ++nt)
            bv[nt] = bi[n0 + wc * 64 + nt * 16 + ccol];
    }

#pragma unroll
    for (int mt = 0; mt < 4; ++mt) {
#pragma unroll
        for (int nt = 0; nt < 4; ++nt) {
            const float badd = (MODE == 0 || MODE == 4) ? bv[nt] : 0.0f;
#pragma unroll
            for (int r = 0; r < 4; ++r)
                tw[(crow + r) * 72 + nt * 16 + ccol] = (__bf16)(acc[mt][nt][r] + badd);
        }
        bf16x8 va = *(const bf16x8*)&tw[r0 * 72 + cseg];
        bf16x8 vb = *(const bf16x8*)&tw[(r0 + 8) * 72 + cseg];

        const int gm_a = m0 + wr * 64 + mt * 16 + r0;
        const int gm_b = gm_a + 8;
        const int gn = n0 + wc * 64 + cseg;

        if (MODE == 0) {
            *(bf16x8*)&C[(size_t)gm_a * N + gn] = va;
            *(bf16x8*)&C[(size_t)gm_b * N + gn] = vb;
        } else if (MODE == 5) {
            // e = exp((s + gate*d1)/32 + mask); unnormalized store + row sums
            const float da = d1f[wr * 64 + mt * 16 + r0];
            const float db = d1f[wr * 64 + mt * 16 + r0 + 8];
            const long long ra = ((long long)bz * M + gm_a) * N + gn;
            const long long rb = ((long long)bz * M + gm_b) * N + gn;
            const int4 ra0 = *(const int4*)&rel[ra];
            const int4 ra1 = *(const int4*)&rel[ra + 4];
            const int4 rb0 = *(const int4*)&rel[rb];
            const int4 rb1 = *(const int4*)&rel[rb + 4];
            const float4 mk0 = *(const float4*)&maskp[(size_t)bz * N + gn];
            const float4 mk1 = *(const float4*)&maskp[(size_t)bz * N + gn + 4];
            const int rlsa[8] = {ra0.x, ra0.y, ra0.z, ra0.w, ra1.x, ra1.y, ra1.z, ra1.w};
            const int rlsb[8] = {rb0.x, rb0.y, rb0.z, rb0.w, rb1.x, rb1.y, rb1.z, rb1.w};
            const float mks[8] = {mk0.x, mk0.y, mk0.z, mk0.w, mk1.x, mk1.y, mk1.z, mk1.w};
            bf16x8 oa, ob;
            float sa = 0.f, sb = 0.f;
#pragma unroll
            for (int j = 0; j < 8; ++j) {
                const float ea = __expf(((float)va[j] + (rlsa[j] == 1 ? da : 0.f))
                                        * 0.03125f + mks[j]);
                const float eb = __expf(((float)vb[j] + (rlsb[j] == 1 ? db : 0.f))
                                        * 0.03125f + mks[j]);
                sa += ea; sb += eb;
                oa[j] = (__bf16)ea; ob[j] = (__bf16)eb;
            }
            // reduce over the 8 lanes sharing each row (cseg groups)
#pragma unroll
            for (int off = 4; off; off >>= 1) {
                sa += __shfl_down(sa, off, 64);
                sb += __shfl_down(sb, off, 64);
            }
            if ((lane & 7) == 0) {
                atomicAdd(&rowsum[(size_t)bz * M + gm_a], sa);
                atomicAdd(&rowsum[(size_t)bz * M + gm_b], sb);
            }
            *(bf16x8*)&C[(size_t)gm_a * N + gn] = oa;
            *(bf16x8*)&C[(size_t)gm_b * N + gn] = ob;
        } else if (MODE == 6) {
            const float inva = 1.0f / rowsum[(size_t)bz * M + gm_a];
            const float invb = 1.0f / rowsum[(size_t)bz * M + gm_b];
            bf16x8 oa, ob;
#pragma unroll
            for (int j = 0; j < 8; ++j) {
                oa[j] = (__bf16)((float)va[j] * inva);
                ob[j] = (__bf16)((float)vb[j] * invb);
            }
            *(bf16x8*)&C[(size_t)gm_a * N + gn] = oa;
            *(bf16x8*)&C[(size_t)gm_b * N + gn] = ob;
        } else {  // MODE 4: + residual (bf16), bf16 out
            const bf16x8 xa = *(const bf16x8*)&resid[(size_t)gm_a * N + gn];
            const bf16x8 xb = *(const bf16x8*)&resid[(size_t)gm_b * N + gn];
            bf16x8 oa, ob;
#pragma unroll
            for (int j = 0; j < 8; ++j) {
                oa[j] = (__bf16)((float)va[j] + (float)xa[j]);
                ob[j] = (__bf16)((float)vb[j] + (float)xb[j]);
            }
            *(bf16x8*)&C[(size_t)gm_a * N + gn] = oa;
            *(bf16x8*)&C[(size_t)gm_b * N + gn] = ob;
        }
    }
}

// LayerNorm over H=1024, bf16 in / fp32 out. 2 rows per 256-thr block.
__global__ __launch_bounds__(256)
void ln_kernel(const bf16_t* __restrict__ x, const float* __restrict__ gamma,
               const float* __restrict__ beta, float* __restrict__ out)
{
    const int H = 1024;
    const int tid = threadIdx.x;
    const int half = tid >> 7;
    const int t7 = tid & 127;
    const size_t row = (size_t)blockIdx.x * 2 + half;
    const int w = tid >> 6, lane = tid & 63;
    const bf16x8 xv = *(const bf16x8*)(x + row * H + t7 * 8);
    float v[8], s = 0.0f, s2 = 0.0f;
#pragma unroll
    for (int j = 0; j < 8; ++j) {
        v[j] = (float)xv[j];
        s += v[j]; s2 += v[j] * v[j];
    }
#pragma unroll
    for (int off = 32; off; off >>= 1) {
        s += __shfl_xor(s, off, 64);
        s2 += __shfl_xor(s2, off, 64);
    }
    __shared__ float rs[4], rs2[4];
    if (lane == 0) { rs[w] = s; rs2[w] = s2; }
    __syncthreads();
    s  = rs[half * 2] + rs[half * 2 + 1];
    s2 = rs2[half * 2] + rs2[half * 2 + 1];
    const float mu  = s * (1.0f / H);
    const float var = s2 * (1.0f / H) - mu * mu;
    const float inv = rsqrtf(var + 1e-12f);
    const int c = t7 * 8;
    float4 o0, o1;
    o0.x = (v[0] - mu) * inv * gamma[c + 0] + beta[c + 0];
    o0.y = (v[1] - mu) * inv * gamma[c + 1] + beta[c + 1];
    o0.z = (v[2] - mu) * inv * gamma[c + 2] + beta[c + 2];
    o0.w = (v[3] - mu) * inv * gamma[c + 3] + beta[c + 3];
    o1.x = (v[4] - mu) * inv * gamma[c + 4] + beta[c + 4];
    o1.y = (v[5] - mu) * inv * gamma[c + 5] + beta[c + 5];
    o1.z = (v[6] - mu) * inv * gamma[c + 6] + beta[c + 6];
    o1.w = (v[7] - mu) * inv * gamma[c + 7] + beta[c + 7];
    *(float4*)(out + row * H + c) = o0;
    *(float4*)(out + row * H + c + 4) = o1;
}

extern "C" void kernel_launch(void* const* d_in, const int* in_sizes, int n_in,
                              void* d_out, int out_size, void* d_ws, size_t ws_size,
                              hipStream_t stream)
{
    constexpr int B = 4, S = 2048, H = 1024;
    const float* hid = (const float*)d_in[0];
    const float* am  = (const float*)d_in[1];
    const int*   rel = (const int*)d_in[2];
    const float* Wq  = (const float*)d_in[3];
    const float* bq  = (const float*)d_in[4];
    const float* Wk  = (const float*)d_in[5];
    const float* bk  = (const float*)d_in[6];
    const float* Wv  = (const float*)d_in[7];
    const float* bv  = (const float*)d_in[8];
    const float* de  = (const float*)d_in[9];
    const float* Wo  = (const float*)d_in[10];
    const float* bo  = (const float*)d_in[11];
    const float* lng = (const float*)d_in[12];
    const float* lnb = (const float*)d_in[13];
    float* out = (float*)d_out;

    char* ws = (char*)d_ws;
    const int n_tok = B * S;                               // 8192
    const size_t MB = 1024 * 1024;
    bf16_t* hidb = (bf16_t*)(ws);                          // 16 MB
    bf16_t* Wqb  = (bf16_t*)(ws + 16 * MB);                // 2 MB each; Wq/Wk/Wv/Wo contiguous
    bf16_t* Wob  = (bf16_t*)(ws + 22 * MB);
    bf16_t* qb   = (bf16_t*)(ws + 24 * MB);                // 16 MB
    bf16_t* kb   = (bf16_t*)(ws + 40 * MB);                // 16 MB
    bf16_t* vT   = (bf16_t*)(ws + 56 * MB);                // 16 MB (B, DH, S)
    bf16_t* ctx  = (bf16_t*)(ws + 72 * MB);                // 16 MB
    bf16_t* sc   = (bf16_t*)(ws + 88 * MB);                // 32 MB (B,S,S) unnormalized exp
    bf16_t* xb   = (bf16_t*)(ws + 88 * MB);                // 16 MB, ALIASES sc (sc dead after PV)
    float*  rowsum = (float*)(ws + 120 * MB);              // 32 KB

    const dim3 blk(256);
    // hid + weights fp32->bf16 + rowsum zeroing, one launch
    cvt_all_kernel<<<dim3(8192 + 4 * 1024 + 8), blk, 0, stream>>>(
        hid, Wq, Wk, Wv, Wo, hidb, Wqb, rowsum);

    // Q + K + V projections fused over z (B = 2 MB/layer fits per-XCD L2),
    // GM=8 swizzle: 64 m-tiles x 8 n-tiles per z-layer.
    gemm_bt<0, 1><<<dim3(64 * 8, 1, 3), blk, 0, stream>>>(
        hidb, Wqb, bq, bk, bv, qb, vT, n_tok, H, H,
        0, 0, (long long)n_tok * H,
        nullptr, nullptr, nullptr, nullptr, nullptr, S, H);
    // scores -> unnormalized exp probs + row sums (softmax kernel eliminated)
    gemm_bt<5, 1><<<dim3(16 * 16, 1, B), blk, 0, stream>>>(
        qb, kb, nullptr, nullptr, nullptr, sc, nullptr, S, S, H,
        (long long)S * H, (long long)S * H, (long long)S * S,
        nullptr, rel, am, de + H, rowsum, S, H);
    // ctx = (exp-scores @ v) / rowsum  (deferred normalization in epilogue)
    gemm_bt<6, 0><<<dim3(H / BN, S / BM, B), blk, 0, stream>>>(
        sc, vT, nullptr, nullptr, nullptr, ctx, nullptr, S, H, S,
        (long long)S * S, (long long)H * S, (long long)S * H,
        nullptr, nullptr, nullptr, nullptr, rowsum, S, H);
    // attn_out = ctx @ Wo^T + bo; x = attn_out + hidden(bf16)  (aliases sc)
    gemm_bt<4, 0><<<dim3(H / BN, n_tok / BM, 1), blk, 0, stream>>>(
        ctx, Wob, bo, nullptr, nullptr, xb, nullptr, n_tok, H, H, 0, 0, 0,
        hidb, nullptr, nullptr, nullptr, nullptr, S, H);
    ln_kernel<<<dim3(n_tok / 2), blk, 0, stream>>>(xb, lng, lnb, out);
}

// Round 12
// 376.910 us; speedup vs baseline: 1.0248x; 1.0122x over previous
//
#include <hip/hip_runtime.h>

#define BM 128
#define BN 128
#define BKH 32   // K-half; one barrier pair covers 2 halves (BK=64)

typedef __bf16 bf16x8 __attribute__((ext_vector_type(8)));
typedef __bf16 bf16x4 __attribute__((ext_vector_type(4)));
typedef float f32x4 __attribute__((ext_vector_type(4)));
typedef __bf16 bf16_t;

__device__ __forceinline__ void gl_lds16(const void* g, void* l) {
    __builtin_amdgcn_global_load_lds(
        (const __attribute__((address_space(1))) void*)g,
        (__attribute__((address_space(3))) void*)l, 16, 0, 0);
}

// fp32 -> bf16 conversion for hid + 4 weight matrices, plus rowsum zeroing,
// in ONE launch.
__global__ __launch_bounds__(256)
void cvt_all_kernel(const float* __restrict__ hid,
                    const float* __restrict__ w0, const float* __restrict__ w1,
                    const float* __restrict__ w2, const float* __restrict__ w3,
                    bf16_t* __restrict__ hidb, bf16_t* __restrict__ wb,
                    float* __restrict__ rowsum)
{
    const int bid = blockIdx.x;
    if (bid >= 12288) {
        const int i = (bid - 12288) * 1024 + threadIdx.x * 4;
        *(float4*)(rowsum + i) = make_float4(0.f, 0.f, 0.f, 0.f);
        return;
    }
    const float* src;
    bf16_t* dst;
    size_t off;
    if (bid < 8192) {
        src = hid; dst = hidb; off = (size_t)bid * 1024;
    } else {
        const int i = (bid - 8192) >> 10;
        src = (i == 0) ? w0 : (i == 1) ? w1 : (i == 2) ? w2 : w3;
        dst = wb + (size_t)i * 1024 * 1024;
        off = (size_t)((bid - 8192) & 1023) * 1024;
    }
    const size_t idx = off + threadIdx.x * 4;
    const float4 v = *(const float4*)(src + idx);
    bf16x4 o;
    o[0] = (__bf16)v.x; o[1] = (__bf16)v.y;
    o[2] = (__bf16)v.z; o[3] = (__bf16)v.w;
    *(bf16x4*)(dst + idx) = o;
}

// Generic NT GEMM: C[m,n] = sum_k A[m,k] * Bw[n,k]  (+ epilogue per MODE)
// MODE 0: QKV fused over z: z=0 Wq/bq; z=1 Wk/bk; z=2 Wv/bv -> vT transposed
// MODE 4: + bias[n] + resid[m,n] (bf16), bf16 out      [out-proj + residual]
// MODE 5: scores+exp: in-loop d1 from A-fragments; epilogue PREFETCHES all
//         rel/mask loads before the LDS transpose (latency pipelined), then
//         e = exp((acc + (rel==1)?d1)/32 + mask), atomicAdds row sums,
//         stores unnormalized e (softmax kernel eliminated).
// MODE 6: PV with deferred normalization: epilogue multiplies by 1/rowsum.
// SWIZ=1: 1D x-grid, grouped decode (GM=8). SWIZ=0: plain 2D.
template <int MODE, int SWIZ>
__global__ __launch_bounds__(256)
void gemm_bt(const bf16_t* __restrict__ A, const bf16_t* __restrict__ Bw,
             const float* __restrict__ bias, const float* __restrict__ bias2,
             const float* __restrict__ bias3,
             bf16_t* __restrict__ C, bf16_t* __restrict__ C2,
             int M, int N, int K,
             long long sAz, long long sBz, long long sCz,
             const bf16_t* __restrict__ resid,
             const int* __restrict__ rel, const float* __restrict__ maskp,
             const float* __restrict__ de1, float* __restrict__ rowsum,
             int Sdim, int DHdim)
{
    const int bz = blockIdx.z;
    const float* bi = bias;
    if (MODE == 0) {
        Bw += (long long)bz * N * K;        // Wq | Wk | Wv contiguous
        bi = (bz == 0) ? bias : (bz == 1 ? bias2 : bias3);
        if (bz < 2) C += (long long)bz * sCz;
    } else {
        A += (long long)bz * sAz;
        Bw += (long long)bz * sBz;
        C += (long long)bz * sCz;
    }

    int m0, n0;
    if (SWIZ) {
        const int num_n = N / BN;
        const int pid = blockIdx.x;
        const int group = 8 * num_n;         // 8 m-tiles per group
        const int g = pid / group;
        m0 = (g * 8 + (pid % 8)) * BM;
        n0 = ((pid % group) / 8) * BN;
    } else {
        m0 = blockIdx.y * BM;
        n0 = blockIdx.x * BN;
    }
    const int tid = threadIdx.x;
    const int w = tid >> 6;          // wave id 0..3
    const int lane = tid & 63;
    const int wr = w >> 1;           // wave row (2x2 wave grid, 64x64 each)
    const int wc = w & 1;
    const int srow = lane >> 2;      // staging: row within 16-row slice
    const int scol = (lane & 3) * 8; // staging: bf16 col offset (16B chunks)
    const int frow = lane & 15;      // fragment m/n index
    const int fk = (lane >> 4) * 8;  // fragment k base
    // epilogue lane decode (needed early for MODE 5 prefetch)
    const int r0 = lane >> 3;        // 0..7 : row within 16-slice
    const int cseg = (lane & 7) * 8; // 8-col segment base

    __shared__ bf16_t smem[4 * BM * BKH];   // 32 KB: A0 | A1 | B0 | B1
    bf16_t* A0 = smem;
    bf16_t* A1 = smem + BM * BKH;
    bf16_t* B0 = smem + 2 * BM * BKH;
    bf16_t* B1 = smem + 3 * BM * BKH;
    // d1 scratch for MODE 5: aliases B0 region (dead after mainloop), 512 B
    float* d1f = (float*)(smem + 2 * BM * BKH);

    f32x4 acc[4][4];
#pragma unroll
    for (int i = 0; i < 4; ++i)
#pragma unroll
        for (int j = 0; j < 4; ++j) acc[i][j] = (f32x4)0.0f;

    float d1acc[4] = {0.f, 0.f, 0.f, 0.f};

    for (int k0 = 0; k0 < K; k0 += 2 * BKH) {
#pragma unroll
        for (int i = 0; i < 2; ++i) {
            const int r = i * 64 + w * 16;
            const bf16_t* ga = A + (size_t)(m0 + r + srow) * K + (k0 + scol);
            const bf16_t* gb = Bw + (size_t)(n0 + r + srow) * K + (k0 + scol);
            gl_lds16(ga,        &A0[r * BKH]);
            gl_lds16(ga + BKH,  &A1[r * BKH]);
            gl_lds16(gb,        &B0[r * BKH]);
            gl_lds16(gb + BKH,  &B1[r * BKH]);
        }
        __syncthreads();
#pragma unroll
        for (int h = 0; h < 2; ++h) {
            const bf16_t* Ah = h ? A1 : A0;
            const bf16_t* Bh = h ? B1 : B0;
            bf16x8 af[4], bfv[4];
#pragma unroll
            for (int t = 0; t < 4; ++t) {
                af[t]  = *(const bf16x8*)&Ah[(wr * 64 + t * 16 + frow) * BKH + fk];
                bfv[t] = *(const bf16x8*)&Bh[(wc * 64 + t * 16 + frow) * BKH + fk];
            }
            if (MODE == 5 && wc == 0) {
                // d1 partial from already-loaded A fragments
                const float* dp = de1 + k0 + h * BKH + fk;
                const float4 e0 = *(const float4*)dp;
                const float4 e1 = *(const float4*)(dp + 4);
#pragma unroll
                for (int t = 0; t < 4; ++t) {
                    d1acc[t] += (float)af[t][0] * e0.x + (float)af[t][1] * e0.y
                              + (float)af[t][2] * e0.z + (float)af[t][3] * e0.w
                              + (float)af[t][4] * e1.x + (float)af[t][5] * e1.y
                              + (float)af[t][6] * e1.z + (float)af[t][7] * e1.w;
                }
            }
#pragma unroll
            for (int mt = 0; mt < 4; ++mt)
#pragma unroll
                for (int nt = 0; nt < 4; ++nt)
                    acc[mt][nt] = __builtin_amdgcn_mfma_f32_16x16x32_bf16(
                        af[mt], bfv[nt], acc[mt][nt], 0, 0, 0);
        }
        __syncthreads();
    }
    // After the final __syncthreads all LDS reads are drained; smem reusable.

    // ---- MODE 5: prefetch ALL epilogue globals BEFORE any dependent work ----
    // Addresses depend only on lane decode; issuing here lets the ~500-900 cyc
    // rel latency overlap the d1 reduce + LDS transpose (R2->R3 lesson).
    int4 relv[4][4];
    float4 mkv0, mkv1;
    if (MODE == 5) {
        const int gn = n0 + wc * 64 + cseg;
#pragma unroll
        for (int mt = 0; mt < 4; ++mt) {
            const int gm_a = m0 + wr * 64 + mt * 16 + r0;
            const long long ra = ((long long)bz * M + gm_a) * N + gn;
            const long long rb = ((long long)bz * M + gm_a + 8) * N + gn;
            relv[mt][0] = *(const int4*)&rel[ra];
            relv[mt][1] = *(const int4*)&rel[ra + 4];
            relv[mt][2] = *(const int4*)&rel[rb];
            relv[mt][3] = *(const int4*)&rel[rb + 4];
        }
        mkv0 = *(const float4*)&maskp[(size_t)bz * N + gn];
        mkv1 = *(const float4*)&maskp[(size_t)bz * N + gn + 4];

        // finish d1: reduce over fk-groups (lanes ^16, ^32 share frow)
        if (wc == 0) {
#pragma unroll
            for (int t = 0; t < 4; ++t) {
                float s = d1acc[t];
                s += __shfl_xor(s, 16, 64);
                s += __shfl_xor(s, 32, 64);
                if (lane < 16) d1f[wr * 64 + t * 16 + lane] = s;
            }
        }
        __syncthreads();
    }

    // C/D layout: col = lane&15, row = (lane>>4)*4 + reg
    const int crow = (lane >> 4) * 4;
    const int ccol = lane & 15;

    if (MODE == 0 && bz == 2) {
        // V projection: transposed store vT[b][n][s]
#pragma unroll
        for (int mt = 0; mt < 4; ++mt) {
            const int mb = m0 + wr * 64 + mt * 16 + crow;
#pragma unroll
            for (int nt = 0; nt < 4; ++nt) {
                const int n = n0 + wc * 64 + nt * 16 + ccol;
                const float bv = bi[n];
                const int b = mb >> 11;      // S = 2048 tokens per batch
                const int s = mb & 2047;
                union { ushort4 u; bf16_t h[4]; } pk;
#pragma unroll
                for (int r = 0; r < 4; ++r) pk.h[r] = (__bf16)(acc[mt][nt][r] + bv);
                *(ushort4*)&C2[(size_t)b * DHdim * Sdim + (size_t)n * Sdim + s] = pk.u;
            }
        }
        return;
    }

    // ---- transpose epilogue ----
    bf16_t* tw = smem + w * (16 * 72);

    float bv[4];
    if (MODE == 0 || MODE == 4) {
#pragma unroll
        for (int nt = 0; nt < 4; ++nt)
            bv[nt] = bi[n0 + wc * 64 + nt * 16 + ccol];
    }

#pragma unroll
    for (int mt = 0; mt < 4; ++mt) {
#pragma unroll
        for (int nt = 0; nt < 4; ++nt) {
            const float badd = (MODE == 0 || MODE == 4) ? bv[nt] : 0.0f;
#pragma unroll
            for (int r = 0; r < 4; ++r)
                tw[(crow + r) * 72 + nt * 16 + ccol] = (__bf16)(acc[mt][nt][r] + badd);
        }
        bf16x8 va = *(const bf16x8*)&tw[r0 * 72 + cseg];
        bf16x8 vb = *(const bf16x8*)&tw[(r0 + 8) * 72 + cseg];

        const int gm_a = m0 + wr * 64 + mt * 16 + r0;
        const int gm_b = gm_a + 8;
        const int gn = n0 + wc * 64 + cseg;

        if (MODE == 0) {
            *(bf16x8*)&C[(size_t)gm_a * N + gn] = va;
            *(bf16x8*)&C[(size_t)gm_b * N + gn] = vb;
        } else if (MODE == 5) {
            // e = exp((s + gate*d1)/32 + mask); unnormalized store + row sums
            const float da = d1f[wr * 64 + mt * 16 + r0];
            const float db = d1f[wr * 64 + mt * 16 + r0 + 8];
            const int rlsa[8] = {relv[mt][0].x, relv[mt][0].y, relv[mt][0].z,
                                 relv[mt][0].w, relv[mt][1].x, relv[mt][1].y,
                                 relv[mt][1].z, relv[mt][1].w};
            const int rlsb[8] = {relv[mt][2].x, relv[mt][2].y, relv[mt][2].z,
                                 relv[mt][2].w, relv[mt][3].x, relv[mt][3].y,
                                 relv[mt][3].z, relv[mt][3].w};
            const float mks[8] = {mkv0.x, mkv0.y, mkv0.z, mkv0.w,
                                  mkv1.x, mkv1.y, mkv1.z, mkv1.w};
            bf16x8 oa, ob;
            float sa = 0.f, sb = 0.f;
#pragma unroll
            for (int j = 0; j < 8; ++j) {
                const float ea = __expf(((float)va[j] + (rlsa[j] == 1 ? da : 0.f))
                                        * 0.03125f + mks[j]);
                const float eb = __expf(((float)vb[j] + (rlsb[j] == 1 ? db : 0.f))
                                        * 0.03125f + mks[j]);
                sa += ea; sb += eb;
                oa[j] = (__bf16)ea; ob[j] = (__bf16)eb;
            }
            // reduce over the 8 lanes sharing each row (cseg groups)
#pragma unroll
            for (int off = 4; off; off >>= 1) {
                sa += __shfl_down(sa, off, 64);
                sb += __shfl_down(sb, off, 64);
            }
            if ((lane & 7) == 0) {
                atomicAdd(&rowsum[(size_t)bz * M + gm_a], sa);
                atomicAdd(&rowsum[(size_t)bz * M + gm_b], sb);
            }
            *(bf16x8*)&C[(size_t)gm_a * N + gn] = oa;
            *(bf16x8*)&C[(size_t)gm_b * N + gn] = ob;
        } else if (MODE == 6) {
            const float inva = 1.0f / rowsum[(size_t)bz * M + gm_a];
            const float invb = 1.0f / rowsum[(size_t)bz * M + gm_b];
            bf16x8 oa, ob;
#pragma unroll
            for (int j = 0; j < 8; ++j) {
                oa[j] = (__bf16)((float)va[j] * inva);
                ob[j] = (__bf16)((float)vb[j] * invb);
            }
            *(bf16x8*)&C[(size_t)gm_a * N + gn] = oa;
            *(bf16x8*)&C[(size_t)gm_b * N + gn] = ob;
        } else {  // MODE 4: + residual (bf16), bf16 out
            const bf16x8 xa = *(const bf16x8*)&resid[(size_t)gm_a * N + gn];
            const bf16x8 xb = *(const bf16x8*)&resid[(size_t)gm_b * N + gn];
            bf16x8 oa, ob;
#pragma unroll
            for (int j = 0; j < 8; ++j) {
                oa[j] = (__bf16)((float)va[j] + (float)xa[j]);
                ob[j] = (__bf16)((float)vb[j] + (float)xb[j]);
            }
            *(bf16x8*)&C[(size_t)gm_a * N + gn] = oa;
            *(bf16x8*)&C[(size_t)gm_b * N + gn] = ob;
        }
    }
}

// LayerNorm over H=1024, bf16 in / fp32 out. 2 rows per 256-thr block.
__global__ __launch_bounds__(256)
void ln_kernel(const bf16_t* __restrict__ x, const float* __restrict__ gamma,
               const float* __restrict__ beta, float* __restrict__ out)
{
    const int H = 1024;
    const int tid = threadIdx.x;
    const int half = tid >> 7;
    const int t7 = tid & 127;
    const size_t row = (size_t)blockIdx.x * 2 + half;
    const int w = tid >> 6, lane = tid & 63;
    const bf16x8 xv = *(const bf16x8*)(x + row * H + t7 * 8);
    float v[8], s = 0.0f, s2 = 0.0f;
#pragma unroll
    for (int j = 0; j < 8; ++j) {
        v[j] = (float)xv[j];
        s += v[j]; s2 += v[j] * v[j];
    }
#pragma unroll
    for (int off = 32; off; off >>= 1) {
        s += __shfl_xor(s, off, 64);
        s2 += __shfl_xor(s2, off, 64);
    }
    __shared__ float rs[4], rs2[4];
    if (lane == 0) { rs[w] = s; rs2[w] = s2; }
    __syncthreads();
    s  = rs[half * 2] + rs[half * 2 + 1];
    s2 = rs2[half * 2] + rs2[half * 2 + 1];
    const float mu  = s * (1.0f / H);
    const float var = s2 * (1.0f / H) - mu * mu;
    const float inv = rsqrtf(var + 1e-12f);
    const int c = t7 * 8;
    float4 o0, o1;
    o0.x = (v[0] - mu) * inv * gamma[c + 0] + beta[c + 0];
    o0.y = (v[1] - mu) * inv * gamma[c + 1] + beta[c + 1];
    o0.z = (v[2] - mu) * inv * gamma[c + 2] + beta[c + 2];
    o0.w = (v[3] - mu) * inv * gamma[c + 3] + beta[c + 3];
    o1.x = (v[4] - mu) * inv * gamma[c + 4] + beta[c + 4];
    o1.y = (v[5] - mu) * inv * gamma[c + 5] + beta[c + 5];
    o1.z = (v[6] - mu) * inv * gamma[c + 6] + beta[c + 6];
    o1.w = (v[7] - mu) * inv * gamma[c + 7] + beta[c + 7];
    *(float4*)(out + row * H + c) = o0;
    *(float4*)(out + row * H + c + 4) = o1;
}

extern "C" void kernel_launch(void* const* d_in, const int* in_sizes, int n_in,
                              void* d_out, int out_size, void* d_ws, size_t ws_size,
                              hipStream_t stream)
{
    constexpr int B = 4, S = 2048, H = 1024;
    const float* hid = (const float*)d_in[0];
    const float* am  = (const float*)d_in[1];
    const int*   rel = (const int*)d_in[2];
    const float* Wq  = (const float*)d_in[3];
    const float* bq  = (const float*)d_in[4];
    const float* Wk  = (const float*)d_in[5];
    const float* bk  = (const float*)d_in[6];
    const float* Wv  = (const float*)d_in[7];
    const float* bv  = (const float*)d_in[8];
    const float* de  = (const float*)d_in[9];
    const float* Wo  = (const float*)d_in[10];
    const float* bo  = (const float*)d_in[11];
    const float* lng = (const float*)d_in[12];
    const float* lnb = (const float*)d_in[13];
    float* out = (float*)d_out;

    char* ws = (char*)d_ws;
    const int n_tok = B * S;                               // 8192
    const size_t MB = 1024 * 1024;
    bf16_t* hidb = (bf16_t*)(ws);                          // 16 MB
    bf16_t* Wqb  = (bf16_t*)(ws + 16 * MB);                // 2 MB each; Wq/Wk/Wv/Wo contiguous
    bf16_t* Wob  = (bf16_t*)(ws + 22 * MB);
    bf16_t* qb   = (bf16_t*)(ws + 24 * MB);                // 16 MB
    bf16_t* kb   = (bf16_t*)(ws + 40 * MB);                // 16 MB
    bf16_t* vT   = (bf16_t*)(ws + 56 * MB);                // 16 MB (B, DH, S)
    bf16_t* ctx  = (bf16_t*)(ws + 72 * MB);                // 16 MB
    bf16_t* sc   = (bf16_t*)(ws + 88 * MB);                // 32 MB (B,S,S) unnormalized exp
    bf16_t* xb   = (bf16_t*)(ws + 88 * MB);                // 16 MB, ALIASES sc (sc dead after PV)
    float*  rowsum = (float*)(ws + 120 * MB);              // 32 KB

    const dim3 blk(256);
    // hid + weights fp32->bf16 + rowsum zeroing, one launch
    cvt_all_kernel<<<dim3(8192 + 4 * 1024 + 8), blk, 0, stream>>>(
        hid, Wq, Wk, Wv, Wo, hidb, Wqb, rowsum);

    // Q + K + V projections fused over z (B = 2 MB/layer fits per-XCD L2),
    // GM=8 swizzle: 64 m-tiles x 8 n-tiles per z-layer.
    gemm_bt<0, 1><<<dim3(64 * 8, 1, 3), blk, 0, stream>>>(
        hidb, Wqb, bq, bk, bv, qb, vT, n_tok, H, H,
        0, 0, (long long)n_tok * H,
        nullptr, nullptr, nullptr, nullptr, nullptr, S, H);
    // scores -> unnormalized exp probs + row sums (prefetched epilogue)
    gemm_bt<5, 1><<<dim3(16 * 16, 1, B), blk, 0, stream>>>(
        qb, kb, nullptr, nullptr, nullptr, sc, nullptr, S, S, H,
        (long long)S * H, (long long)S * H, (long long)S * S,
        nullptr, rel, am, de + H, rowsum, S, H);
    // ctx = (exp-scores @ v) / rowsum  (deferred normalization in epilogue)
    gemm_bt<6, 0><<<dim3(H / BN, S / BM, B), blk, 0, stream>>>(
        sc, vT, nullptr, nullptr, nullptr, ctx, nullptr, S, H, S,
        (long long)S * S, (long long)H * S, (long long)S * H,
        nullptr, nullptr, nullptr, nullptr, rowsum, S, H);
    // attn_out = ctx @ Wo^T + bo; x = attn_out + hidden(bf16)  (aliases sc)
    gemm_bt<4, 0><<<dim3(H / BN, n_tok / BM, 1), blk, 0, stream>>>(
        ctx, Wob, bo, nullptr, nullptr, xb, nullptr, n_tok, H, H, 0, 0, 0,
        hidb, nullptr, nullptr, nullptr, nullptr, S, H);
    ln_kernel<<<dim3(n_tok / 2), blk, 0, stream>>>(xb, lng, lnb, out);
}